// Round 1
// baseline (15354.855 us; speedup 1.0000x reference)
//
#include <hip/hip_runtime.h>
#include <hip/hip_bf16.h>

// LBEBM: Langevin prior sampling (20 steps through EBM fwd+bwd) + decoder MLP.
// fp32 baseline, fused per-workgroup Langevin (all 20 steps LDS-resident).

#define NTOT 65536

__device__ __forceinline__ float gelu_f(float x) {
    return 0.5f * x * (1.0f + erff(x * 0.70710678118654752440f));
}
__device__ __forceinline__ float gelu_grad_f(float x) {
    float cdf = 0.5f * (1.0f + erff(x * 0.70710678118654752440f));
    float pdf = 0.3989422804014326779f * __expf(-0.5f * x * x);
    return cdf + x * pdf;
}

__global__ void transpose_w2_kernel(const float* __restrict__ w2, float* __restrict__ w2t) {
    int idx = blockIdx.x * blockDim.x + threadIdx.x;
    if (idx < 200 * 200) {
        int k = idx / 200, j = idx - k * 200;
        w2t[j * 200 + k] = w2[idx];
    }
}

// 32 samples per workgroup, 512 threads, ~109KB LDS (1 wg/CU, 8 waves).
__global__ __launch_bounds__(512) void langevin_kernel(
    const float* __restrict__ ftraj, const float* __restrict__ z0,
    const float* __restrict__ noise,
    const float* __restrict__ w1, const float* __restrict__ b1,
    const float* __restrict__ w2, const float* __restrict__ b2,
    const float* __restrict__ w3, const float* __restrict__ b3,
    const float* __restrict__ w2t, float* __restrict__ zout)
{
    __shared__ float zc[32][32];      // [z(0..15) | cond(16..31)]
    __shared__ float h1T[200][32];    // gelu(u1), transposed (k-major)
    __shared__ float u1[32][201];     // pre-act L1; overwritten by dh1 in bwd
    __shared__ float h2s[32][201];    // gelu(u2)
    __shared__ float u2T[200][32];    // pre-act L2 transposed; overwritten by dh2T
    __shared__ float g3[32][21];      // logits -> -softmax

    const int tid = threadIdx.x;
    const int gbase = blockIdx.x * 32;
    const int jj = tid & 255;
    const int half = tid >> 8;

    // load z0 and cond
    {
        int s = tid >> 4, i = tid & 15;   // 512 = 32*16
        zc[s][i]      = z0[(gbase + s) * 16 + i];
        zc[s][16 + i] = ftraj[(gbase + s) * 16 + i];
    }
    __syncthreads();

    for (int t = 0; t < 20; ++t) {
        // ---- Phase A: u1 = [z|c] @ w1 + b1 ; h1 = gelu(u1) ----
        for (int idx = tid; idx < 32 * 200; idx += 512) {
            int s = idx / 200, j = idx - s * 200;
            float acc = b1[j];
            #pragma unroll
            for (int k = 0; k < 32; ++k) acc += zc[s][k] * w1[k * 200 + j];
            u1[s][j] = acc;
            h1T[j][s] = gelu_f(acc);
        }
        __syncthreads();

        // ---- Phase B: u2 = h1 @ w2 + b2 ; h2 = gelu(u2) ----
        if (jj < 200) {
            float bb = b2[jj];
            #pragma unroll
            for (int sb = 0; sb < 2; ++sb) {
                const int s0 = (half * 2 + sb) * 8;
                float acc[8];
                #pragma unroll
                for (int i = 0; i < 8; ++i) acc[i] = bb;
                #pragma unroll 4
                for (int k = 0; k < 200; ++k) {
                    float w = w2[k * 200 + jj];
                    float4 ha = *(const float4*)&h1T[k][s0];
                    float4 hb = *(const float4*)&h1T[k][s0 + 4];
                    acc[0] += ha.x * w; acc[1] += ha.y * w;
                    acc[2] += ha.z * w; acc[3] += ha.w * w;
                    acc[4] += hb.x * w; acc[5] += hb.y * w;
                    acc[6] += hb.z * w; acc[7] += hb.w * w;
                }
                #pragma unroll
                for (int i = 0; i < 8; ++i) {
                    float v = acc[i];
                    u2T[jj][s0 + i] = v;
                    h2s[s0 + i][jj] = gelu_f(v);
                }
            }
        }
        __syncthreads();

        // ---- Phase C: logits = h2 @ w3 + b3 ; g3 = -softmax(logits) ----
        for (int idx = tid; idx < 32 * 20; idx += 512) {
            int s = idx / 20, j = idx - s * 20;
            float acc = b3[j];
            #pragma unroll 4
            for (int k = 0; k < 200; ++k) acc += h2s[s][k] * w3[k * 20 + j];
            g3[s][j] = acc;
        }
        __syncthreads();
        if (tid < 32) {
            int s = tid;
            float m = -1e30f;
            #pragma unroll
            for (int j = 0; j < 20; ++j) m = fmaxf(m, g3[s][j]);
            float e[20];
            float sum = 0.f;
            #pragma unroll
            for (int j = 0; j < 20; ++j) { e[j] = __expf(g3[s][j] - m); sum += e[j]; }
            float inv = 1.0f / sum;
            #pragma unroll
            for (int j = 0; j < 20; ++j) g3[s][j] = -e[j] * inv;
        }
        __syncthreads();

        // ---- Phase D: dh2 = (g3 @ w3^T) * gelu'(u2)  (in place into u2T) ----
        for (int idx = tid; idx < 32 * 200; idx += 512) {
            int s = idx & 31, k = idx >> 5;
            float acc = 0.f;
            #pragma unroll
            for (int j = 0; j < 20; ++j) acc += g3[s][j] * w3[k * 20 + j];
            float u = u2T[k][s];
            u2T[k][s] = acc * gelu_grad_f(u);
        }
        __syncthreads();

        // ---- Phase E: dh1 = (dh2 @ w2^T) * gelu'(u1)  (in place into u1) ----
        if (jj < 200) {
            #pragma unroll
            for (int sb = 0; sb < 2; ++sb) {
                const int s0 = (half * 2 + sb) * 8;
                float acc[8];
                #pragma unroll
                for (int i = 0; i < 8; ++i) acc[i] = 0.f;
                #pragma unroll 4
                for (int j = 0; j < 200; ++j) {
                    float w = w2t[j * 200 + jj];   // = w2[jj][j]
                    float4 da = *(const float4*)&u2T[j][s0];
                    float4 db = *(const float4*)&u2T[j][s0 + 4];
                    acc[0] += da.x * w; acc[1] += da.y * w;
                    acc[2] += da.z * w; acc[3] += da.w * w;
                    acc[4] += db.x * w; acc[5] += db.y * w;
                    acc[6] += db.z * w; acc[7] += db.w * w;
                }
                #pragma unroll
                for (int i = 0; i < 8; ++i) {
                    int s = s0 + i;
                    float u = u1[s][jj];
                    u1[s][jj] = acc[i] * gelu_grad_f(u);
                }
            }
        }
        __syncthreads();

        // ---- Phase F: gz = dh1 @ w1[:16]^T ; Langevin update ----
        {
            int s = tid >> 4, i = tid & 15;  // 512 = 32*16, all active
            float g = 0.f;
            #pragma unroll 4
            for (int k = 0; k < 200; ++k) g += u1[s][k] * w1[i * 200 + k];
            float z = zc[s][i];
            size_t nidx = ((size_t)t * NTOT + (gbase + s)) * 16 + i;
            float eps = noise[nidx];
            zc[s][i] = z - 0.08f * (g + 0.25f * z) + 0.4f * eps;
        }
        __syncthreads();
    }

    // write final z
    {
        int s = tid >> 4, i = tid & 15;
        zout[(gbase + s) * 16 + i] = zc[s][i];
    }
}

// 16 samples per workgroup, 512 threads, ~100KB LDS.
__global__ __launch_bounds__(512) void decoder_kernel(
    const float* __restrict__ ftraj, const float* __restrict__ zfin,
    const float* __restrict__ w1, const float* __restrict__ b1,
    const float* __restrict__ w2, const float* __restrict__ b2,
    const float* __restrict__ w3, const float* __restrict__ b3,
    const float* __restrict__ w4, const float* __restrict__ b4,
    float* __restrict__ out)
{
    __shared__ float xin[16][33];
    __shared__ float aT[1024][16];   // h1, then h3 (k-major)
    __shared__ float bT[512][16];    // h2 (k-major)
    __shared__ float l4p[160];

    const int tid = threadIdx.x;
    const int gbase = blockIdx.x * 16;

    if (tid < 16 * 32) {
        int s = tid >> 5, c = tid & 31;
        float v = (c < 16) ? ftraj[(gbase + s) * 16 + c]
                           : zfin[(gbase + s) * 16 + (c - 16)];
        xin[s][c] = v;
    }
    __syncthreads();

    // L1: 32 -> 1024, relu
    for (int idx = tid; idx < 16 * 1024; idx += 512) {
        int s = idx & 15, j = idx >> 4;
        float acc = b1[j];
        #pragma unroll
        for (int k = 0; k < 32; ++k) acc += xin[s][k] * w1[k * 1024 + j];
        aT[j][s] = fmaxf(acc, 0.f);
    }
    __syncthreads();

    // L2: 1024 -> 512, relu. one column per thread, 16 samples in registers.
    {
        int j = tid;
        float acc[16];
        float bb = b2[j];
        #pragma unroll
        for (int i = 0; i < 16; ++i) acc[i] = bb;
        #pragma unroll 2
        for (int k = 0; k < 1024; ++k) {
            float w = w2[k * 512 + j];
            const float4* hp = (const float4*)(&aT[k][0]);
            float4 h0 = hp[0], h1v = hp[1], h2v = hp[2], h3v = hp[3];
            acc[0]  += h0.x * w;  acc[1]  += h0.y * w;
            acc[2]  += h0.z * w;  acc[3]  += h0.w * w;
            acc[4]  += h1v.x * w; acc[5]  += h1v.y * w;
            acc[6]  += h1v.z * w; acc[7]  += h1v.w * w;
            acc[8]  += h2v.x * w; acc[9]  += h2v.y * w;
            acc[10] += h2v.z * w; acc[11] += h2v.w * w;
            acc[12] += h3v.x * w; acc[13] += h3v.y * w;
            acc[14] += h3v.z * w; acc[15] += h3v.w * w;
        }
        #pragma unroll
        for (int i = 0; i < 16; ++i) bT[j][i] = fmaxf(acc[i], 0.f);
    }
    __syncthreads();

    // L3: 512 -> 1024, relu. two column passes.
    #pragma unroll
    for (int p = 0; p < 2; ++p) {
        int j = tid + p * 512;
        float acc[16];
        float bb = b3[j];
        #pragma unroll
        for (int i = 0; i < 16; ++i) acc[i] = bb;
        #pragma unroll 2
        for (int k = 0; k < 512; ++k) {
            float w = w3[k * 1024 + j];
            const float4* hp = (const float4*)(&bT[k][0]);
            float4 h0 = hp[0], h1v = hp[1], h2v = hp[2], h3v = hp[3];
            acc[0]  += h0.x * w;  acc[1]  += h0.y * w;
            acc[2]  += h0.z * w;  acc[3]  += h0.w * w;
            acc[4]  += h1v.x * w; acc[5]  += h1v.y * w;
            acc[6]  += h1v.z * w; acc[7]  += h1v.w * w;
            acc[8]  += h2v.x * w; acc[9]  += h2v.y * w;
            acc[10] += h2v.z * w; acc[11] += h2v.w * w;
            acc[12] += h3v.x * w; acc[13] += h3v.y * w;
            acc[14] += h3v.z * w; acc[15] += h3v.w * w;
        }
        #pragma unroll
        for (int i = 0; i < 16; ++i) aT[j][i] = fmaxf(acc[i], 0.f);
    }
    __syncthreads();

    // L4: 1024 -> 10. split K in two halves across 320 threads.
    float accl4 = 0.f;
    if (tid < 320) {
        int r = (tid < 160) ? tid : tid - 160;
        int p = (tid < 160) ? 0 : 1;
        int s = r & 15, j = r >> 4;
        float acc = (p == 0) ? b4[j] : 0.f;
        #pragma unroll 4
        for (int k = p * 512; k < p * 512 + 512; ++k)
            acc += aT[k][s] * w4[k * 10 + j];
        if (p == 1) l4p[r] = acc; else accl4 = acc;
    }
    __syncthreads();
    if (tid < 160) {
        int s = tid & 15, j = tid >> 4;
        out[(size_t)(gbase + s) * 10 + j] = accl4 + l4p[tid];
    }
}

__global__ void copy_ftraj_kernel(const float4* __restrict__ src, float4* __restrict__ dst) {
    int idx = blockIdx.x * blockDim.x + threadIdx.x;
    dst[idx] = src[idx];
}

extern "C" void kernel_launch(void* const* d_in, const int* in_sizes, int n_in,
                              void* d_out, int out_size, void* d_ws, size_t ws_size,
                              hipStream_t stream)
{
    const float* ftraj = (const float*)d_in[0];
    const float* z0    = (const float*)d_in[1];
    const float* noise = (const float*)d_in[2];
    const float* ew1 = (const float*)d_in[3];
    const float* eb1 = (const float*)d_in[4];
    const float* ew2 = (const float*)d_in[5];
    const float* eb2 = (const float*)d_in[6];
    const float* ew3 = (const float*)d_in[7];
    const float* eb3 = (const float*)d_in[8];
    const float* dw1 = (const float*)d_in[9];
    const float* db1 = (const float*)d_in[10];
    const float* dw2 = (const float*)d_in[11];
    const float* db2 = (const float*)d_in[12];
    const float* dw3 = (const float*)d_in[13];
    const float* db3 = (const float*)d_in[14];
    const float* dw4 = (const float*)d_in[15];
    const float* db4 = (const float*)d_in[16];
    float* out = (float*)d_out;

    float* w2t  = (float*)d_ws;                        // 160 KB
    float* zfin = (float*)((char*)d_ws + 256 * 1024);  // 4 MB

    transpose_w2_kernel<<<(200 * 200 + 511) / 512, 512, 0, stream>>>(ew2, w2t);
    langevin_kernel<<<NTOT / 32, 512, 0, stream>>>(ftraj, z0, noise,
                                                   ew1, eb1, ew2, eb2, ew3, eb3,
                                                   w2t, zfin);
    decoder_kernel<<<NTOT / 16, 512, 0, stream>>>(ftraj, zfin,
                                                  dw1, db1, dw2, db2,
                                                  dw3, db3, dw4, db4, out);
    copy_ftraj_kernel<<<512, 512, 0, stream>>>((const float4*)ftraj,
                                               (float4*)(out + NTOT * 10));
}

// Round 2
// 14035.397 us; speedup vs baseline: 1.0940x; 1.0940x over previous
//
#include <hip/hip_runtime.h>
#include <hip/hip_bf16.h>

// LBEBM: Langevin prior sampling (20 steps through EBM fwd+bwd) + decoder MLP.
// fp32, fused per-workgroup Langevin. R2: bank-conflict-free LDS layouts,
// w1/w3/biases cached in LDS, noise prefetch, decoder stride padding.

#define NTOT 65536

__device__ __forceinline__ float gelu_f(float x) {
    return 0.5f * x * (1.0f + erff(x * 0.70710678118654752440f));
}
__device__ __forceinline__ float gelu_grad_f(float x) {
    float cdf = 0.5f * (1.0f + erff(x * 0.70710678118654752440f));
    float pdf = 0.3989422804014326779f * __expf(-0.5f * x * x);
    return cdf + x * pdf;
}

__global__ void transpose_w2_kernel(const float* __restrict__ w2, float* __restrict__ w2t) {
    int idx = blockIdx.x * blockDim.x + threadIdx.x;
    if (idx < 200 * 200) {
        int k = idx / 200, j = idx - k * 200;
        w2t[j * 200 + k] = w2[idx];
    }
}

// 32 samples per workgroup, 512 threads, ~153KB LDS (1 wg/CU, 8 waves).
__global__ __launch_bounds__(512) void langevin_kernel(
    const float* __restrict__ ftraj, const float* __restrict__ z0,
    const float* __restrict__ noise,
    const float* __restrict__ w1, const float* __restrict__ b1,
    const float* __restrict__ w2, const float* __restrict__ b2,
    const float* __restrict__ w3, const float* __restrict__ b3,
    const float* __restrict__ w2t, float* __restrict__ zout)
{
    __shared__ float zc[32][33];      // [z(0..15) | cond(16..31)], padded
    __shared__ float u1[32][201];     // pre-act L1; overwritten by dh1 in bwd
    __shared__ float h1T[200][32];    // gelu(u1) k-major; reused as dh2T in bwd
    __shared__ float u2s[32][201];    // pre-act L2, sample-major
    __shared__ float h2s[32][201];    // gelu(u2), sample-major
    __shared__ float g3[32][21];      // logits -> -softmax
    __shared__ float w1L[32][201];    // w1 cached (padded rows for phase F)
    __shared__ float w3L[200][20];    // w3 cached
    __shared__ float b1L[200], b2L[200], b3L[20];

    const int tid = threadIdx.x;
    const int gbase = blockIdx.x * 32;
    const int jj = tid & 255;
    const int half = tid >> 8;
    const int s16 = tid >> 4, i16 = tid & 15;   // 512 = 32 samples x 16 dims
    const int sA = tid & 31;                    // sample-inner lane mapping

    // stage weights + biases into LDS (reused across 20 steps)
    for (int idx = tid; idx < 32 * 200; idx += 512) {
        int k = idx / 200, j = idx - k * 200;
        w1L[k][j] = w1[idx];
    }
    for (int idx = tid; idx < 200 * 20; idx += 512) {
        int k = idx / 20, j = idx - k * 20;
        w3L[k][j] = w3[idx];
    }
    if (tid < 200) { b1L[tid] = b1[tid]; b2L[tid] = b2[tid]; }
    if (tid < 20)  { b3L[tid] = b3[tid]; }

    // load z0 and cond
    zc[s16][i16]      = z0[(gbase + s16) * 16 + i16];
    zc[s16][16 + i16] = ftraj[(gbase + s16) * 16 + i16];
    __syncthreads();

    float eps = noise[(size_t)(gbase + s16) * 16 + i16];   // t=0 prefetched

    for (int t = 0; t < 20; ++t) {
        // prefetch next step's noise early (hide HBM latency under phases A-E)
        float eps_next = 0.f;
        if (t < 19)
            eps_next = noise[((size_t)(t + 1) * NTOT + gbase + s16) * 16 + i16];

        // ---- Phase A: u1 = [z|c] @ w1 + b1 ; h1 = gelu(u1) ----
        // lanes vary sample (sA) -> all LDS writes conflict-free.
        {
            float zr[32];
            #pragma unroll
            for (int k = 0; k < 32; ++k) zr[k] = zc[sA][k];
            for (int idx = tid; idx < 32 * 200; idx += 512) {
                int j = idx >> 5;
                float acc = b1L[j];
                #pragma unroll
                for (int k = 0; k < 32; ++k) acc += zr[k] * w1L[k][j];
                u1[sA][j] = acc;
                h1T[j][sA] = gelu_f(acc);
            }
        }
        __syncthreads();

        // ---- Phase B: u2 = h1 @ w2 + b2 ; h2 = gelu(u2) ----
        if (jj < 200) {
            float bb = b2L[jj];
            #pragma unroll
            for (int sb = 0; sb < 2; ++sb) {
                const int s0 = (half * 2 + sb) * 8;
                float acc[8];
                #pragma unroll
                for (int i = 0; i < 8; ++i) acc[i] = bb;
                #pragma unroll 4
                for (int k = 0; k < 200; ++k) {
                    float w = w2[k * 200 + jj];
                    float4 ha = *(const float4*)&h1T[k][s0];
                    float4 hb = *(const float4*)&h1T[k][s0 + 4];
                    acc[0] += ha.x * w; acc[1] += ha.y * w;
                    acc[2] += ha.z * w; acc[3] += ha.w * w;
                    acc[4] += hb.x * w; acc[5] += hb.y * w;
                    acc[6] += hb.z * w; acc[7] += hb.w * w;
                }
                #pragma unroll
                for (int i = 0; i < 8; ++i) {
                    float v = acc[i];
                    u2s[s0 + i][jj] = v;            // consecutive jj -> conflict-free
                    h2s[s0 + i][jj] = gelu_f(v);
                }
            }
        }
        __syncthreads();

        // ---- Phase C: logits = h2 @ w3 + b3 ----
        for (int idx = tid; idx < 32 * 20; idx += 512) {
            int s = idx / 20, j = idx - s * 20;
            float acc = b3L[j];
            #pragma unroll 4
            for (int k = 0; k < 200; ++k) acc += h2s[s][k] * w3L[k][j];
            g3[s][j] = acc;
        }
        __syncthreads();

        // ---- softmax: g3 <- -softmax(logits) ----
        if (tid < 32) {
            int s = tid;
            float m = -1e30f;
            #pragma unroll
            for (int j = 0; j < 20; ++j) m = fmaxf(m, g3[s][j]);
            float e[20];
            float sum = 0.f;
            #pragma unroll
            for (int j = 0; j < 20; ++j) { e[j] = __expf(g3[s][j] - m); sum += e[j]; }
            float inv = 1.0f / sum;
            #pragma unroll
            for (int j = 0; j < 20; ++j) g3[s][j] = -e[j] * inv;
        }
        __syncthreads();

        // ---- Phase D: dh2T = (g3 @ w3^T) * gelu'(u2), stored into h1T ----
        for (int idx = tid; idx < 32 * 200; idx += 512) {
            int s = idx & 31, k = idx >> 5;
            float acc = 0.f;
            #pragma unroll
            for (int j = 0; j < 20; ++j) acc += g3[s][j] * w3L[k][j];
            float u = u2s[s][k];
            h1T[k][s] = acc * gelu_grad_f(u);       // consecutive s -> conflict-free
        }
        __syncthreads();

        // ---- Phase E: dh1 = (dh2 @ w2^T) * gelu'(u1)  (in place into u1) ----
        if (jj < 200) {
            #pragma unroll
            for (int sb = 0; sb < 2; ++sb) {
                const int s0 = (half * 2 + sb) * 8;
                float acc[8];
                #pragma unroll
                for (int i = 0; i < 8; ++i) acc[i] = 0.f;
                #pragma unroll 4
                for (int j = 0; j < 200; ++j) {
                    float w = w2t[j * 200 + jj];    // = w2[jj][j]
                    float4 da = *(const float4*)&h1T[j][s0];
                    float4 db = *(const float4*)&h1T[j][s0 + 4];
                    acc[0] += da.x * w; acc[1] += da.y * w;
                    acc[2] += da.z * w; acc[3] += da.w * w;
                    acc[4] += db.x * w; acc[5] += db.y * w;
                    acc[6] += db.z * w; acc[7] += db.w * w;
                }
                #pragma unroll
                for (int i = 0; i < 8; ++i) {
                    int s = s0 + i;
                    float u = u1[s][jj];
                    u1[s][jj] = acc[i] * gelu_grad_f(u);
                }
            }
        }
        __syncthreads();

        // ---- Phase F: gz = dh1 @ w1[:16]^T ; Langevin update ----
        {
            float g = 0.f;
            #pragma unroll 4
            for (int k = 0; k < 200; ++k) g += u1[s16][k] * w1L[i16][k];
            float z = zc[s16][i16];
            zc[s16][i16] = z - 0.08f * (g + 0.25f * z) + 0.4f * eps;
            eps = eps_next;
        }
        __syncthreads();
    }

    // write final z
    zout[(gbase + s16) * 16 + i16] = zc[s16][i16];
}

// 16 samples per workgroup, 512 threads. stride padded to 20 (float4-aligned,
// breaks the 32-way write conflict of stride 16).
#define DP 20
__global__ __launch_bounds__(512) void decoder_kernel(
    const float* __restrict__ ftraj, const float* __restrict__ zfin,
    const float* __restrict__ w1, const float* __restrict__ b1,
    const float* __restrict__ w2, const float* __restrict__ b2,
    const float* __restrict__ w3, const float* __restrict__ b3,
    const float* __restrict__ w4, const float* __restrict__ b4,
    float* __restrict__ out)
{
    __shared__ float xin[16][33];
    __shared__ float aT[1024][DP];   // h1, then h3 (k-major)
    __shared__ float bT[512][DP];    // h2 (k-major)
    __shared__ float l4p[160];

    const int tid = threadIdx.x;
    const int gbase = blockIdx.x * 16;

    if (tid < 16 * 32) {
        int s = tid >> 5, c = tid & 31;
        float v = (c < 16) ? ftraj[(gbase + s) * 16 + c]
                           : zfin[(gbase + s) * 16 + (c - 16)];
        xin[s][c] = v;
    }
    __syncthreads();

    // L1: 32 -> 1024, relu
    for (int idx = tid; idx < 16 * 1024; idx += 512) {
        int s = idx & 15, j = idx >> 4;
        float acc = b1[j];
        #pragma unroll
        for (int k = 0; k < 32; ++k) acc += xin[s][k] * w1[k * 1024 + j];
        aT[j][s] = fmaxf(acc, 0.f);
    }
    __syncthreads();

    // L2: 1024 -> 512, relu. one column per thread, 16 samples in registers.
    {
        int j = tid;
        float acc[16];
        float bb = b2[j];
        #pragma unroll
        for (int i = 0; i < 16; ++i) acc[i] = bb;
        #pragma unroll 2
        for (int k = 0; k < 1024; ++k) {
            float w = w2[k * 512 + j];
            const float4* hp = (const float4*)(&aT[k][0]);
            float4 h0 = hp[0], h1v = hp[1], h2v = hp[2], h3v = hp[3];
            acc[0]  += h0.x * w;  acc[1]  += h0.y * w;
            acc[2]  += h0.z * w;  acc[3]  += h0.w * w;
            acc[4]  += h1v.x * w; acc[5]  += h1v.y * w;
            acc[6]  += h1v.z * w; acc[7]  += h1v.w * w;
            acc[8]  += h2v.x * w; acc[9]  += h2v.y * w;
            acc[10] += h2v.z * w; acc[11] += h2v.w * w;
            acc[12] += h3v.x * w; acc[13] += h3v.y * w;
            acc[14] += h3v.z * w; acc[15] += h3v.w * w;
        }
        #pragma unroll
        for (int i = 0; i < 16; ++i) bT[j][i] = fmaxf(acc[i], 0.f);
    }
    __syncthreads();

    // L3: 512 -> 1024, relu. two column passes.
    #pragma unroll
    for (int p = 0; p < 2; ++p) {
        int j = tid + p * 512;
        float acc[16];
        float bb = b3[j];
        #pragma unroll
        for (int i = 0; i < 16; ++i) acc[i] = bb;
        #pragma unroll 2
        for (int k = 0; k < 512; ++k) {
            float w = w3[k * 1024 + j];
            const float4* hp = (const float4*)(&bT[k][0]);
            float4 h0 = hp[0], h1v = hp[1], h2v = hp[2], h3v = hp[3];
            acc[0]  += h0.x * w;  acc[1]  += h0.y * w;
            acc[2]  += h0.z * w;  acc[3]  += h0.w * w;
            acc[4]  += h1v.x * w; acc[5]  += h1v.y * w;
            acc[6]  += h1v.z * w; acc[7]  += h1v.w * w;
            acc[8]  += h2v.x * w; acc[9]  += h2v.y * w;
            acc[10] += h2v.z * w; acc[11] += h2v.w * w;
            acc[12] += h3v.x * w; acc[13] += h3v.y * w;
            acc[14] += h3v.z * w; acc[15] += h3v.w * w;
        }
        #pragma unroll
        for (int i = 0; i < 16; ++i) aT[j][i] = fmaxf(acc[i], 0.f);
    }
    __syncthreads();

    // L4: 1024 -> 10. split K in two halves across 320 threads.
    float accl4 = 0.f;
    if (tid < 320) {
        int r = (tid < 160) ? tid : tid - 160;
        int p = (tid < 160) ? 0 : 1;
        int s = r & 15, j = r >> 4;
        float acc = (p == 0) ? b4[j] : 0.f;
        #pragma unroll 4
        for (int k = p * 512; k < p * 512 + 512; ++k)
            acc += aT[k][s] * w4[k * 10 + j];
        if (p == 1) l4p[r] = acc; else accl4 = acc;
    }
    __syncthreads();
    if (tid < 160) {
        int s = tid & 15, j = tid >> 4;
        out[(size_t)(gbase + s) * 10 + j] = accl4 + l4p[tid];
    }
}

__global__ void copy_ftraj_kernel(const float4* __restrict__ src, float4* __restrict__ dst) {
    int idx = blockIdx.x * blockDim.x + threadIdx.x;
    dst[idx] = src[idx];
}

extern "C" void kernel_launch(void* const* d_in, const int* in_sizes, int n_in,
                              void* d_out, int out_size, void* d_ws, size_t ws_size,
                              hipStream_t stream)
{
    const float* ftraj = (const float*)d_in[0];
    const float* z0    = (const float*)d_in[1];
    const float* noise = (const float*)d_in[2];
    const float* ew1 = (const float*)d_in[3];
    const float* eb1 = (const float*)d_in[4];
    const float* ew2 = (const float*)d_in[5];
    const float* eb2 = (const float*)d_in[6];
    const float* ew3 = (const float*)d_in[7];
    const float* eb3 = (const float*)d_in[8];
    const float* dw1 = (const float*)d_in[9];
    const float* db1 = (const float*)d_in[10];
    const float* dw2 = (const float*)d_in[11];
    const float* db2 = (const float*)d_in[12];
    const float* dw3 = (const float*)d_in[13];
    const float* db3 = (const float*)d_in[14];
    const float* dw4 = (const float*)d_in[15];
    const float* db4 = (const float*)d_in[16];
    float* out = (float*)d_out;

    float* w2t  = (float*)d_ws;                        // 160 KB
    float* zfin = (float*)((char*)d_ws + 256 * 1024);  // 4 MB

    transpose_w2_kernel<<<(200 * 200 + 511) / 512, 512, 0, stream>>>(ew2, w2t);
    langevin_kernel<<<NTOT / 32, 512, 0, stream>>>(ftraj, z0, noise,
                                                   ew1, eb1, ew2, eb2, ew3, eb3,
                                                   w2t, zfin);
    decoder_kernel<<<NTOT / 16, 512, 0, stream>>>(ftraj, zfin,
                                                  dw1, db1, dw2, db2,
                                                  dw3, db3, dw4, db4, out);
    copy_ftraj_kernel<<<512, 512, 0, stream>>>((const float4*)ftraj,
                                               (float4*)(out + NTOT * 10));
}

// Round 4
// 5539.812 us; speedup vs baseline: 2.7717x; 2.5336x over previous
//
#include <hip/hip_runtime.h>
#include <hip/hip_bf16.h>

// LBEBM R4: langevin = exact fp32, register-blocked, conflict-audited,
//           phase-E transpose bug fixed (reads w2 row-major directly).
//           decoder = bf16 MFMA with fp32 z hand-off + hi/lo split L1 input.

#define NTOT 65536

typedef __attribute__((ext_vector_type(8))) short bf16x8;
typedef __attribute__((ext_vector_type(4))) float f32x4;
typedef __attribute__((ext_vector_type(4))) unsigned short u16x4;

__device__ __forceinline__ unsigned short f2bf(float f) {
    union { float f; unsigned int u; } v; v.f = f;
    unsigned int r = v.u + 0x7fffu + ((v.u >> 16) & 1u);
    return (unsigned short)(r >> 16);
}
__device__ __forceinline__ float bf2f(unsigned short h) {
    union { unsigned int u; float f; } v; v.u = ((unsigned int)h) << 16;
    return v.f;
}
// gelu value + derivative from one erf + one exp
__device__ __forceinline__ void gelu_pair(float x, float& val, float& grad) {
    float cdf = 0.5f * (1.0f + erff(x * 0.70710678118654752440f));
    float pdf = 0.3989422804014326779f * __expf(-0.5f * x * x);
    val = x * cdf;
    grad = cdf + x * pdf;
}

// dst[n][k] (Nrows x Kp, bf16) = src[k][n] (K x Nsrc, f32), zero-padded.
__global__ void prep_wT_kernel(const float* __restrict__ src, unsigned short* __restrict__ dst,
                               int K, int Kp, int Nsrc, int Nrows) {
    int idx = blockIdx.x * blockDim.x + threadIdx.x;
    if (idx >= Nrows * Kp) return;
    int n = idx / Kp, k = idx - n * Kp;
    float v = (k < K && n < Nsrc) ? src[(size_t)k * Nsrc + n] : 0.f;
    dst[idx] = f2bf(v);
}

// ---------------- Langevin: 32 samples/wg, 512 threads, ~154KB LDS ----------------
__global__ __launch_bounds__(512) void langevin_kernel(
    const float* __restrict__ ftraj, const float* __restrict__ z0,
    const float* __restrict__ noise,
    const float* __restrict__ w1, const float* __restrict__ b1,
    const float* __restrict__ w2, const float* __restrict__ b2,
    const float* __restrict__ w3, const float* __restrict__ b3,
    float* __restrict__ zout)
{
    __shared__ float zcT[32][36];     // zcT[k][s]: k<16 z, k>=16 cond
    __shared__ float h1T[200][36];    // fwd h1; C/F split-K partials; D: dh2T
    __shared__ float h2T[200][36];    // fwd h2; E: dh1T
    __shared__ float d1T[200][36];    // gelu'(u1)
    __shared__ float d2T[200][36];    // gelu'(u2)
    __shared__ float g3T[20][36];     // -softmax(logits), [y][s]
    __shared__ float w3L[200][21];
    __shared__ float w1FL[16][204];   // w1 rows 0..15 (for phase F)
    __shared__ float b1L[200], b2L[200], b3L[20];

    const int tid = threadIdx.x;
    const int gbase = blockIdx.x * 32;
    const int s16 = tid >> 4, i16 = tid & 15;
    float* const sp = &h1T[0][0];     // split-K partial buffer (aliases h1T)

    for (int idx = tid; idx < 200 * 20; idx += 512) {
        int k = idx / 20, y = idx - k * 20;
        w3L[k][y] = w3[idx];
    }
    for (int idx = tid; idx < 16 * 200; idx += 512) {
        int i = idx / 200, k = idx - i * 200;
        w1FL[i][k] = w1[idx];          // idx == i*200+k
    }
    if (tid < 200) { b1L[tid] = b1[tid]; b2L[tid] = b2[tid]; }
    if (tid < 20)  { b3L[tid] = b3[tid]; }
    zcT[i16][s16]      = z0[(size_t)(gbase + s16) * 16 + i16];
    zcT[16 + i16][s16] = ftraj[(size_t)(gbase + s16) * 16 + i16];
    __syncthreads();

    float eps = noise[(size_t)(gbase + s16) * 16 + i16];

    const int jq = tid >> 2;          // 0..127 (use <100)
    const int j0 = jq * 2;
    const int s0 = (tid & 3) * 8;
    const bool act400 = (tid < 400);

    for (int st = 0; st < 20; ++st) {
        float eps_next = 0.f;
        if (st < 19)
            eps_next = noise[((size_t)(st + 1) * NTOT + gbase + s16) * 16 + i16];

        // ---- A: u1 = [z|c] @ w1 + b1 (K=32); h1 = gelu, d1 = gelu' ----
        if (act400) {
            float acc[2][8];
            #pragma unroll
            for (int jj = 0; jj < 2; ++jj) {
                float bb = b1L[j0 + jj];
                #pragma unroll
                for (int ss = 0; ss < 8; ++ss) acc[jj][ss] = bb;
            }
            #pragma unroll 4
            for (int k = 0; k < 32; ++k) {
                float4 zA = *(const float4*)&zcT[k][s0];
                float4 zB = *(const float4*)&zcT[k][s0 + 4];
                float zv[8] = {zA.x, zA.y, zA.z, zA.w, zB.x, zB.y, zB.z, zB.w};
                float2 wq = *(const float2*)&w1[k * 200 + j0];
                #pragma unroll
                for (int ss = 0; ss < 8; ++ss) {
                    acc[0][ss] += wq.x * zv[ss];
                    acc[1][ss] += wq.y * zv[ss];
                }
            }
            #pragma unroll
            for (int jj = 0; jj < 2; ++jj) {
                int j = j0 + jj;
                float hv[8], dv[8];
                #pragma unroll
                for (int ss = 0; ss < 8; ++ss) gelu_pair(acc[jj][ss], hv[ss], dv[ss]);
                *(float4*)&h1T[j][s0]     = make_float4(hv[0], hv[1], hv[2], hv[3]);
                *(float4*)&h1T[j][s0 + 4] = make_float4(hv[4], hv[5], hv[6], hv[7]);
                *(float4*)&d1T[j][s0]     = make_float4(dv[0], dv[1], dv[2], dv[3]);
                *(float4*)&d1T[j][s0 + 4] = make_float4(dv[4], dv[5], dv[6], dv[7]);
            }
        }
        __syncthreads();

        // ---- B: u2 = h1 @ w2 + b2 (K=200); h2 = gelu, d2 = gelu' ----
        if (act400) {
            float acc[2][8];
            #pragma unroll
            for (int jj = 0; jj < 2; ++jj) {
                float bb = b2L[j0 + jj];
                #pragma unroll
                for (int ss = 0; ss < 8; ++ss) acc[jj][ss] = bb;
            }
            #pragma unroll 4
            for (int k = 0; k < 200; ++k) {
                float4 hA = *(const float4*)&h1T[k][s0];
                float4 hB = *(const float4*)&h1T[k][s0 + 4];
                float hv[8] = {hA.x, hA.y, hA.z, hA.w, hB.x, hB.y, hB.z, hB.w};
                float2 wq = *(const float2*)&w2[(size_t)k * 200 + j0];
                #pragma unroll
                for (int ss = 0; ss < 8; ++ss) {
                    acc[0][ss] += wq.x * hv[ss];
                    acc[1][ss] += wq.y * hv[ss];
                }
            }
            #pragma unroll
            for (int jj = 0; jj < 2; ++jj) {
                int j = j0 + jj;
                float hv[8], dv[8];
                #pragma unroll
                for (int ss = 0; ss < 8; ++ss) gelu_pair(acc[jj][ss], hv[ss], dv[ss]);
                *(float4*)&h2T[j][s0]     = make_float4(hv[0], hv[1], hv[2], hv[3]);
                *(float4*)&h2T[j][s0 + 4] = make_float4(hv[4], hv[5], hv[6], hv[7]);
                *(float4*)&d2T[j][s0]     = make_float4(dv[0], dv[1], dv[2], dv[3]);
                *(float4*)&d2T[j][s0 + 4] = make_float4(dv[4], dv[5], dv[6], dv[7]);
            }
        }
        __syncthreads();

        // ---- C: logits partials (split-K 4x50) into sp ----
        {
            const int kc = tid >> 7;              // uniform per 2 waves
            const int rc = tid & 127;
            const int sC0 = (rc >> 5) * 8;
            const int jC = rc & 31;
            if (jC < 20) {
                float acc[8] = {0, 0, 0, 0, 0, 0, 0, 0};
                #pragma unroll 2
                for (int k = kc * 50; k < kc * 50 + 50; ++k) {
                    float4 hA = *(const float4*)&h2T[k][sC0];
                    float4 hB = *(const float4*)&h2T[k][sC0 + 4];
                    float w = w3L[k][jC];
                    acc[0] += hA.x * w; acc[1] += hA.y * w;
                    acc[2] += hA.z * w; acc[3] += hA.w * w;
                    acc[4] += hB.x * w; acc[5] += hB.y * w;
                    acc[6] += hB.z * w; acc[7] += hB.w * w;
                }
                float* p = &sp[kc * 720 + jC * 36 + sC0];
                *(float4*)p       = make_float4(acc[0], acc[1], acc[2], acc[3]);
                *(float4*)(p + 4) = make_float4(acc[4], acc[5], acc[6], acc[7]);
            }
        }
        __syncthreads();

        // ---- combine + softmax: g3T = -softmax(logits) ----
        if (tid < 32) {
            const int s = tid;
            float l[20];
            float m = -1e30f;
            #pragma unroll
            for (int y = 0; y < 20; ++y) {
                float v = b3L[y] + sp[y * 36 + s] + sp[720 + y * 36 + s]
                        + sp[1440 + y * 36 + s] + sp[2160 + y * 36 + s];
                l[y] = v;
                m = fmaxf(m, v);
            }
            float sum = 0.f;
            #pragma unroll
            for (int y = 0; y < 20; ++y) { l[y] = __expf(l[y] - m); sum += l[y]; }
            float inv = -1.0f / sum;
            #pragma unroll
            for (int y = 0; y < 20; ++y) g3T[y][s] = l[y] * inv;
        }
        __syncthreads();

        // ---- D: dh2T = (g3 @ w3^T) * d2  -> h1T ----
        if (act400) {
            const int k0 = j0;
            float acc[2][8] = {};
            #pragma unroll
            for (int y = 0; y < 20; ++y) {
                float4 gA = *(const float4*)&g3T[y][s0];
                float4 gB = *(const float4*)&g3T[y][s0 + 4];
                float gv[8] = {gA.x, gA.y, gA.z, gA.w, gB.x, gB.y, gB.z, gB.w};
                float w0 = w3L[k0][y], w1v = w3L[k0 + 1][y];
                #pragma unroll
                for (int ss = 0; ss < 8; ++ss) {
                    acc[0][ss] += w0 * gv[ss];
                    acc[1][ss] += w1v * gv[ss];
                }
            }
            #pragma unroll
            for (int kk = 0; kk < 2; ++kk) {
                int k = k0 + kk;
                float4 dA = *(const float4*)&d2T[k][s0];
                float4 dB = *(const float4*)&d2T[k][s0 + 4];
                float dd[8] = {dA.x, dA.y, dA.z, dA.w, dB.x, dB.y, dB.z, dB.w};
                float o[8];
                #pragma unroll
                for (int ss = 0; ss < 8; ++ss) o[ss] = acc[kk][ss] * dd[ss];
                *(float4*)&h1T[k][s0]     = make_float4(o[0], o[1], o[2], o[3]);
                *(float4*)&h1T[k][s0 + 4] = make_float4(o[4], o[5], o[6], o[7]);
            }
        }
        __syncthreads();

        // ---- E: dh1 = (dh2 @ w2^T) * d1 -> h2T.  w2 row-major directly! ----
        if (act400) {
            float acc[2][8] = {};
            #pragma unroll 2
            for (int kb = 0; kb < 50; ++kb) {
                const int k = kb * 4;
                float dv[4][8];
                #pragma unroll
                for (int kk = 0; kk < 4; ++kk) {
                    float4 dA = *(const float4*)&h1T[k + kk][s0];
                    float4 dB = *(const float4*)&h1T[k + kk][s0 + 4];
                    dv[kk][0] = dA.x; dv[kk][1] = dA.y; dv[kk][2] = dA.z; dv[kk][3] = dA.w;
                    dv[kk][4] = dB.x; dv[kk][5] = dB.y; dv[kk][6] = dB.z; dv[kk][7] = dB.w;
                }
                float4 wA = *(const float4*)&w2[(size_t)j0 * 200 + k];        // w2[j0][k..k+3]
                float4 wB = *(const float4*)&w2[(size_t)(j0 + 1) * 200 + k];  // w2[j0+1][k..]
                float w0[4] = {wA.x, wA.y, wA.z, wA.w};
                float w1r[4] = {wB.x, wB.y, wB.z, wB.w};
                #pragma unroll
                for (int kk = 0; kk < 4; ++kk)
                    #pragma unroll
                    for (int ss = 0; ss < 8; ++ss) {
                        acc[0][ss] += w0[kk] * dv[kk][ss];
                        acc[1][ss] += w1r[kk] * dv[kk][ss];
                    }
            }
            #pragma unroll
            for (int jj = 0; jj < 2; ++jj) {
                int j = j0 + jj;
                float4 dA = *(const float4*)&d1T[j][s0];
                float4 dB = *(const float4*)&d1T[j][s0 + 4];
                float dd[8] = {dA.x, dA.y, dA.z, dA.w, dB.x, dB.y, dB.z, dB.w};
                float o[8];
                #pragma unroll
                for (int ss = 0; ss < 8; ++ss) o[ss] = acc[jj][ss] * dd[ss];
                *(float4*)&h2T[j][s0]     = make_float4(o[0], o[1], o[2], o[3]);
                *(float4*)&h2T[j][s0 + 4] = make_float4(o[4], o[5], o[6], o[7]);
            }
        }
        __syncthreads();

        // ---- F: gz partials (split-K 8x25) into sp ----
        {
            const int kc = tid >> 6;              // uniform per wave
            const int rF = tid & 63;
            const int iF = rF >> 2;
            const int sF0 = (rF & 3) * 8;
            float acc[8] = {0, 0, 0, 0, 0, 0, 0, 0};
            #pragma unroll 5
            for (int k = kc * 25; k < kc * 25 + 25; ++k) {
                float4 dA = *(const float4*)&h2T[k][sF0];
                float4 dB = *(const float4*)&h2T[k][sF0 + 4];
                float w = w1FL[iF][k];
                acc[0] += dA.x * w; acc[1] += dA.y * w;
                acc[2] += dA.z * w; acc[3] += dA.w * w;
                acc[4] += dB.x * w; acc[5] += dB.y * w;
                acc[6] += dB.z * w; acc[7] += dB.w * w;
            }
            float* p = &sp[kc * 576 + iF * 36 + sF0];
            *(float4*)p       = make_float4(acc[0], acc[1], acc[2], acc[3]);
            *(float4*)(p + 4) = make_float4(acc[4], acc[5], acc[6], acc[7]);
        }
        __syncthreads();

        // ---- update z ----
        {
            float g = 0.f;
            #pragma unroll
            for (int kc = 0; kc < 8; ++kc) g += sp[kc * 576 + i16 * 36 + s16];
            float z = zcT[i16][s16];
            zcT[i16][s16] = z - 0.08f * (g + 0.25f * z) + 0.4f * eps;
            eps = eps_next;
        }
        __syncthreads();
    }

    zout[(size_t)(gbase + s16) * 16 + i16] = zcT[i16][s16];
}

// ---------------- Decoder: bf16 MFMA, 32 samples/wg, 512 threads ----------------
__global__ __launch_bounds__(512) void decoder_kernel(
    const float* __restrict__ ftraj, const float* __restrict__ zfin,
    const unsigned short* __restrict__ wT1, const unsigned short* __restrict__ wT2,
    const unsigned short* __restrict__ wT3, const unsigned short* __restrict__ wT4,
    const float* __restrict__ b1, const float* __restrict__ b2,
    const float* __restrict__ b3, const float* __restrict__ b4,
    float* __restrict__ out)
{
    __shared__ __align__(16) unsigned short xh[32][40];     // input hi
    __shared__ __align__(16) unsigned short xl[32][40];     // input lo
    __shared__ __align__(16) unsigned short hA[32][1032];   // h1 then h3
    __shared__ __align__(16) unsigned short hB[32][520];    // h2; then f32 L4 scratch
    __shared__ float b1L[1024], b2L[512], b3L[1024];

    const int tid = threadIdx.x;
    const int gbase = blockIdx.x * 32;
    const int wv = tid >> 6, l = tid & 63;
    const int lr = l & 15, lg = l >> 4;

    for (int i = tid; i < 1024; i += 512) { b1L[i] = b1[i]; b3L[i] = b3[i]; }
    if (tid < 512) b2L[tid] = b2[tid];
    {
        int s = tid >> 4, c = tid & 15;
        float vf = ftraj[(size_t)(gbase + s) * 16 + c];
        unsigned short fh = f2bf(vf);
        xh[s][c] = fh;
        xl[s][c] = f2bf(vf - bf2f(fh));
        float vz = zfin[(size_t)(gbase + s) * 16 + c];
        unsigned short zh = f2bf(vz);
        xh[s][16 + c] = zh;
        xl[s][16 + c] = f2bf(vz - bf2f(zh));
    }
    __syncthreads();

    // ---- L1: h1 = relu(x @ w1 + b1), K=32, N=1024; hi/lo split input ----
    {
        bf16x8 xhf[2], xlf[2];
        #pragma unroll
        for (int mt = 0; mt < 2; ++mt) {
            xhf[mt] = *(const bf16x8*)&xh[mt * 16 + lr][lg * 8];
            xlf[mt] = *(const bf16x8*)&xl[mt * 16 + lr][lg * 8];
        }
        #pragma unroll 2
        for (int a = 0; a < 8; ++a) {
            const int nt = wv * 8 + a;
            bf16x8 af = *(const bf16x8*)&wT1[(size_t)(nt * 16 + lr) * 40 + lg * 8];
            f32x4 acc0 = {0.f, 0.f, 0.f, 0.f}, acc1 = {0.f, 0.f, 0.f, 0.f};
            acc0 = __builtin_amdgcn_mfma_f32_16x16x32_bf16(af, xhf[0], acc0, 0, 0, 0);
            acc0 = __builtin_amdgcn_mfma_f32_16x16x32_bf16(af, xlf[0], acc0, 0, 0, 0);
            acc1 = __builtin_amdgcn_mfma_f32_16x16x32_bf16(af, xhf[1], acc1, 0, 0, 0);
            acc1 = __builtin_amdgcn_mfma_f32_16x16x32_bf16(af, xlf[1], acc1, 0, 0, 0);
            const int n0 = nt * 16 + lg * 4;
            u16x4 o0, o1;
            #pragma unroll
            for (int r = 0; r < 4; ++r) {
                float bb = b1L[n0 + r];
                o0[r] = f2bf(fmaxf(acc0[r] + bb, 0.f));
                o1[r] = f2bf(fmaxf(acc1[r] + bb, 0.f));
            }
            *(u16x4*)&hA[lr][n0] = o0;
            *(u16x4*)&hA[16 + lr][n0] = o1;
        }
    }
    __syncthreads();

    // ---- L2: h2 = relu(h1 @ w2 + b2), K=1024, N=512 ----
    {
        f32x4 acc[4][2];
        #pragma unroll
        for (int a = 0; a < 4; ++a)
            #pragma unroll
            for (int mt = 0; mt < 2; ++mt) acc[a][mt] = (f32x4){0.f, 0.f, 0.f, 0.f};
        #pragma unroll 2
        for (int ks = 0; ks < 32; ++ks) {
            const int k0 = ks * 32;
            bf16x8 bfr[2];
            #pragma unroll
            for (int mt = 0; mt < 2; ++mt)
                bfr[mt] = *(const bf16x8*)&hA[mt * 16 + lr][k0 + lg * 8];
            #pragma unroll
            for (int a = 0; a < 4; ++a) {
                const int n = (wv * 4 + a) * 16 + lr;
                bf16x8 af = *(const bf16x8*)&wT2[(size_t)n * 1032 + k0 + lg * 8];
                acc[a][0] = __builtin_amdgcn_mfma_f32_16x16x32_bf16(af, bfr[0], acc[a][0], 0, 0, 0);
                acc[a][1] = __builtin_amdgcn_mfma_f32_16x16x32_bf16(af, bfr[1], acc[a][1], 0, 0, 0);
            }
        }
        #pragma unroll
        for (int a = 0; a < 4; ++a) {
            const int n0 = (wv * 4 + a) * 16 + lg * 4;
            #pragma unroll
            for (int mt = 0; mt < 2; ++mt) {
                u16x4 o;
                #pragma unroll
                for (int r = 0; r < 4; ++r)
                    o[r] = f2bf(fmaxf(acc[a][mt][r] + b2L[n0 + r], 0.f));
                *(u16x4*)&hB[mt * 16 + lr][n0] = o;
            }
        }
    }
    __syncthreads();

    // ---- L3: h3 = relu(h2 @ w3 + b3), K=512, N=1024 ----
    {
        f32x4 acc[8][2];
        #pragma unroll
        for (int a = 0; a < 8; ++a)
            #pragma unroll
            for (int mt = 0; mt < 2; ++mt) acc[a][mt] = (f32x4){0.f, 0.f, 0.f, 0.f};
        #pragma unroll 1
        for (int ks = 0; ks < 16; ++ks) {
            const int k0 = ks * 32;
            bf16x8 bfr[2];
            #pragma unroll
            for (int mt = 0; mt < 2; ++mt)
                bfr[mt] = *(const bf16x8*)&hB[mt * 16 + lr][k0 + lg * 8];
            #pragma unroll
            for (int a = 0; a < 8; ++a) {
                const int n = (wv * 8 + a) * 16 + lr;
                bf16x8 af = *(const bf16x8*)&wT3[(size_t)n * 520 + k0 + lg * 8];
                acc[a][0] = __builtin_amdgcn_mfma_f32_16x16x32_bf16(af, bfr[0], acc[a][0], 0, 0, 0);
                acc[a][1] = __builtin_amdgcn_mfma_f32_16x16x32_bf16(af, bfr[1], acc[a][1], 0, 0, 0);
            }
        }
        #pragma unroll
        for (int a = 0; a < 8; ++a) {
            const int n0 = (wv * 8 + a) * 16 + lg * 4;
            #pragma unroll
            for (int mt = 0; mt < 2; ++mt) {
                u16x4 o;
                #pragma unroll
                for (int r = 0; r < 4; ++r)
                    o[r] = f2bf(fmaxf(acc[a][mt][r] + b3L[n0 + r], 0.f));
                *(u16x4*)&hA[mt * 16 + lr][n0] = o;
            }
        }
    }
    __syncthreads();

    // ---- L4: logits = h3 @ w4 + b4, K=1024 split over 8 waves, N=16(pad) ----
    float* pf = (float*)hB;
    {
        f32x4 acc[2];
        acc[0] = (f32x4){0.f, 0.f, 0.f, 0.f};
        acc[1] = (f32x4){0.f, 0.f, 0.f, 0.f};
        #pragma unroll
        for (int q = 0; q < 4; ++q) {
            const int k0 = (wv * 4 + q) * 32;
            bf16x8 af = *(const bf16x8*)&wT4[(size_t)lr * 1032 + k0 + lg * 8];
            #pragma unroll
            for (int mt = 0; mt < 2; ++mt) {
                bf16x8 bfr = *(const bf16x8*)&hA[mt * 16 + lr][k0 + lg * 8];
                acc[mt] = __builtin_amdgcn_mfma_f32_16x16x32_bf16(af, bfr, acc[mt], 0, 0, 0);
            }
        }
        #pragma unroll
        for (int mt = 0; mt < 2; ++mt)
            *(f32x4*)&pf[((wv * 2 + mt) * 64 + l) * 4] = acc[mt];
    }
    __syncthreads();
    {
        const int m = tid & 31, n = tid >> 5;          // n 0..15
        const int lsrc = ((n >> 2) << 4) | (m & 15);
        const int r = n & 3, mt = m >> 4;
        float v = 0.f;
        #pragma unroll
        for (int w = 0; w < 8; ++w)
            v += pf[((w * 2 + mt) * 64 + lsrc) * 4 + r];
        if (n < 10)
            out[(size_t)(gbase + m) * 10 + n] = v + b4[n];
    }
}

__global__ void copy_ftraj_kernel(const float4* __restrict__ src, float4* __restrict__ dst) {
    int idx = blockIdx.x * blockDim.x + threadIdx.x;
    dst[idx] = src[idx];
}

extern "C" void kernel_launch(void* const* d_in, const int* in_sizes, int n_in,
                              void* d_out, int out_size, void* d_ws, size_t ws_size,
                              hipStream_t stream)
{
    const float* ftraj = (const float*)d_in[0];
    const float* z0    = (const float*)d_in[1];
    const float* noise = (const float*)d_in[2];
    const float* ew1 = (const float*)d_in[3];
    const float* eb1 = (const float*)d_in[4];
    const float* ew2 = (const float*)d_in[5];
    const float* eb2 = (const float*)d_in[6];
    const float* ew3 = (const float*)d_in[7];
    const float* eb3 = (const float*)d_in[8];
    const float* dw1 = (const float*)d_in[9];
    const float* db1 = (const float*)d_in[10];
    const float* dw2 = (const float*)d_in[11];
    const float* db2 = (const float*)d_in[12];
    const float* dw3 = (const float*)d_in[13];
    const float* db3 = (const float*)d_in[14];
    const float* dw4 = (const float*)d_in[15];
    const float* db4 = (const float*)d_in[16];
    float* out = (float*)d_out;

    char* ws = (char*)d_ws;
    float* zfin           = (float*)ws;                           // 4 MB fp32
    unsigned short* wsT1  = (unsigned short*)(ws + 4194304);      // 81920 B
    unsigned short* wsT2  = (unsigned short*)(ws + 4276224);      // 1056768 B
    unsigned short* wsT3  = (unsigned short*)(ws + 5332992);      // 1064960 B
    unsigned short* wsT4  = (unsigned short*)(ws + 6397952);      // 33024 B

    prep_wT_kernel<<<(1024 * 40 + 511) / 512, 512, 0, stream>>>(dw1, wsT1, 32, 40, 1024, 1024);
    prep_wT_kernel<<<(512 * 1032 + 511) / 512, 512, 0, stream>>>(dw2, wsT2, 1024, 1032, 512, 512);
    prep_wT_kernel<<<(1024 * 520 + 511) / 512, 512, 0, stream>>>(dw3, wsT3, 512, 520, 1024, 1024);
    prep_wT_kernel<<<(16 * 1032 + 511) / 512, 512, 0, stream>>>(dw4, wsT4, 1024, 1032, 10, 16);

    langevin_kernel<<<NTOT / 32, 512, 0, stream>>>(ftraj, z0, noise,
                                                   ew1, eb1, ew2, eb2, ew3, eb3,
                                                   zfin);
    decoder_kernel<<<NTOT / 32, 512, 0, stream>>>(ftraj, zfin,
                                                  wsT1, wsT2, wsT3, wsT4,
                                                  db1, db2, db3, db4, out);
    copy_ftraj_kernel<<<512, 512, 0, stream>>>((const float4*)ftraj,
                                               (float4*)(out + (size_t)NTOT * 10));
}